// Round 20
// baseline (113.487 us; speedup 1.0000x reference)
//
#include <hip/hip_runtime.h>
#include <stdint.h>

#define EPS 1e-6f

constexpr int D    = 128;   // head_dim
constexpr int SEQ  = 4096;  // seq_len
constexpr int NBH  = 64;    // bsz*num_heads
constexpr int TK   = 16;    // k rows per LDS tile (pass 1)
constexpr int QT   = 64;    // q rows per block (pass 2)

typedef __attribute__((ext_vector_type(8)))  __bf16 bf16x8;
typedef __attribute__((ext_vector_type(4)))  __bf16 bf16x4;
typedef __attribute__((ext_vector_type(4)))  float  f32x4;
typedef __attribute__((ext_vector_type(16))) float  f32x16;

typedef const __attribute__((address_space(1))) uint32_t* as1_u32p;
typedef __attribute__((address_space(3))) uint32_t*       as3_u32p;

__device__ __forceinline__ float phi1(float x) {
    // elu(x)+1 : x>0 -> x+1 ; x<=0 -> exp(x). Branchless.
    return fmaxf(x, 0.0f) + __expf(fminf(x, 0.0f));
}

// ---------------- Pass 1 (MFMA + global_load_lds, depth-3 pipeline, NT loads):
// KVTp[split][bh][e][d] = sum_k V[k][e]*phiK[k][d]  (f32 partials)
// aux=2 (CPol NT) on the K/V streams (268 MB > L3): unlocked pass 1 103 -> ~30 µs (R18).
// R20: partial stores also NT (write-once, read-once-by-reduce) — L3's only steady
// tenant is the 2 MB KVT/Zb that pass 2 re-reads 64x.
__global__ __launch_bounds__(512, 4) void kv_partial_mfma(const float* __restrict__ K,
                                                          const float* __restrict__ V,
                                                          float* __restrict__ KVTp,
                                                          float* __restrict__ Zp,
                                                          int chunk) {
    __shared__ float stile[4][2][TK][D];   // [buf][K|V][k][col] = 64 KB -> 2 blocks/CU

    const int split = blockIdx.x, bh = blockIdx.y;
    const int tid  = threadIdx.x;
    const int lane = tid & 63;
    const int wave = tid >> 6;
    const int k0   = split * chunk;
    const size_t base = (size_t)bh * SEQ * D;

    // staging role: waves 0-3 issue K tile, waves 4-7 issue V tile; 2 x 16B per thread
    const int  mat = wave >> 2;             // 0 = K, 1 = V
    const int  w4  = wave & 3;
    const float* __restrict__ src = mat ? V : K;
    const int eoff0 = (w4 * 2 + 0) * 256 + lane * 4;  // float offset within [16][128] tile
    const int eoff1 = (w4 * 2 + 1) * 256 + lane * 4;

    // compute role: 2e x 4d wave grid
    const int we = wave >> 2;                        // 0..1 -> e-base we*64
    const int wd = wave & 3;                         // 0..3 -> d-strip wd*32
    const int er0 = we * 64 + (lane & 31);           // A row (e), strip 0
    const int er1 = er0 + 32;                        // A row (e), strip 1
    const int dr  = wd * 32 + (lane & 31);           // B col (d)
    const int kh  = (lane >> 5) * 8;                 // k-half of the 16-k step

    f32x16 acc0, acc1;
#pragma unroll
    for (int i = 0; i < 16; ++i) { acc0[i] = 0.f; acc1[i] = 0.f; }
    float zacc = 0.f;
    const bool doZ = (we == 0);   // waves 0-3 own Z for their own d-strip

    const int tiles = chunk / TK;

#define ISSUE(BUF, T) { \
        const float* g = src + base + (size_t)(k0 + (T) * TK) * D; \
        float* l = &stile[BUF][mat][0][0]; \
        __builtin_amdgcn_global_load_lds((as1_u32p)(const void*)(g + eoff0), \
                                         (as3_u32p)(void*)(l + eoff0), 16, 0, 2); \
        __builtin_amdgcn_global_load_lds((as1_u32p)(const void*)(g + eoff1), \
                                         (as3_u32p)(void*)(l + eoff1), 16, 0, 2); }

    // prologue: 3 tiles in flight (6 loads/wave)
    ISSUE(0, 0)
    ISSUE(1, 1)
    ISSUE(2, 2)

    for (int t = 0; t < tiles; ++t) {
        const int buf = t & 3;
        if (t + 3 < tiles) {
            ISSUE((t + 3) & 3, t + 3)
            asm volatile("s_waitcnt vmcnt(6)" ::: "memory");  // t's 2 done; 6 in flight
        } else if (t + 2 < tiles) {
            asm volatile("s_waitcnt vmcnt(4)" ::: "memory");
        } else if (t + 1 < tiles) {
            asm volatile("s_waitcnt vmcnt(2)" ::: "memory");
        } else {
            asm volatile("s_waitcnt vmcnt(0)" ::: "memory");
        }
        __builtin_amdgcn_s_barrier();        // all waves' tile-t writes visible
        __builtin_amdgcn_sched_barrier(0);

        const float* kt = &stile[buf][0][0][0];
        const float* vt = &stile[buf][1][0][0];

        bf16x8 av0, av1, bk;
#pragma unroll
        for (int i = 0; i < 8; ++i) {
            const float fv0 = vt[(kh + i) * D + er0];
            const float fv1 = vt[(kh + i) * D + er1];
            const float p   = phi1(kt[(kh + i) * D + dr]);
            av0[i] = (__bf16)fv0;
            av1[i] = (__bf16)fv1;
            bk[i]  = (__bf16)p;
            if (doZ) zacc += p;
        }
        acc0 = __builtin_amdgcn_mfma_f32_32x32x16_bf16(av0, bk, acc0, 0, 0, 0);
        acc1 = __builtin_amdgcn_mfma_f32_32x32x16_bf16(av1, bk, acc1, 0, 0, 0);

        asm volatile("s_waitcnt lgkmcnt(0)" ::: "memory");   // my ds_reads retired
        __builtin_amdgcn_s_barrier();                         // buf reusable at t+1's ISSUE
        __builtin_amdgcn_sched_barrier(0);
    }
#undef ISSUE

    // store C partials (f32, NT — read once by reduce, no L3 alloc).
    // C/D: col = lane&31, row = (reg&3) + 8*(reg>>2) + 4*(lane>>5)
    float* kvb = KVTp + ((size_t)split * NBH + bh) * D * D;
    const int ebase = we * 64 + 4 * (lane >> 5);
    const int dcol  = wd * 32 + (lane & 31);
#pragma unroll
    for (int r = 0; r < 16; ++r) {
        const int e = ebase + (r & 3) + 8 * (r >> 2);
        __builtin_nontemporal_store(acc0[r], &kvb[(size_t)e * D + dcol]);
        __builtin_nontemporal_store(acc1[r], &kvb[(size_t)(e + 32) * D + dcol]);
    }

    // Z: lane l covers k-half kh at d = dr; lane l^32 covers the other k-half
    if (doZ) {
        zacc += __shfl_xor(zacc, 32);
        if (lane < 32) {
            __builtin_nontemporal_store(zacc,
                Zp + ((size_t)split * NBH + bh) * D + wd * 32 + lane);
        }
    }
}

// ---------------- Reduce partials -> bf16: KVT[bh][e][d], Zb[bh][d]
// NT loads on the partials (stream-once); KVT/Zb stores stay cacheable (pass 2
// re-reads them 64x — the only intended L3 tenant).
__global__ __launch_bounds__(256) void reduce_bf16_kernel(const float* __restrict__ KVTp,
                                                          const float* __restrict__ Zp,
                                                          __bf16* __restrict__ KVT,
                                                          __bf16* __restrict__ Zb,
                                                          int P) {
    constexpr int KVF8 = NBH * D * D / 8;  // 131072
    constexpr int ZF8  = NBH * D / 8;      // 1024
    const int idx = blockIdx.x * 256 + threadIdx.x;
    if (idx < KVF8) {
        const size_t b0 = (size_t)idx * 8;
        f32x4 s0 = __builtin_nontemporal_load((const f32x4*)(KVTp + b0));
        f32x4 s1 = __builtin_nontemporal_load((const f32x4*)(KVTp + b0 + 4));
        for (int s = 1; s < P; ++s) {
            const float* p = KVTp + (size_t)s * NBH * D * D + b0;
            const f32x4 a = __builtin_nontemporal_load((const f32x4*)(p));
            const f32x4 b = __builtin_nontemporal_load((const f32x4*)(p + 4));
            s0 += a;
            s1 += b;
        }
        bf16x8 o;
        o[0] = (__bf16)s0[0]; o[1] = (__bf16)s0[1]; o[2] = (__bf16)s0[2]; o[3] = (__bf16)s0[3];
        o[4] = (__bf16)s1[0]; o[5] = (__bf16)s1[1]; o[6] = (__bf16)s1[2]; o[7] = (__bf16)s1[3];
        *(bf16x8*)(KVT + b0) = o;
    } else if (idx < KVF8 + ZF8) {
        const size_t b0 = (size_t)(idx - KVF8) * 8;
        f32x4 s0 = __builtin_nontemporal_load((const f32x4*)(Zp + b0));
        f32x4 s1 = __builtin_nontemporal_load((const f32x4*)(Zp + b0 + 4));
        for (int s = 1; s < P; ++s) {
            const float* p = Zp + (size_t)s * NBH * D + b0;
            const f32x4 a = __builtin_nontemporal_load((const f32x4*)(p));
            const f32x4 b = __builtin_nontemporal_load((const f32x4*)(p + 4));
            s0 += a;
            s1 += b;
        }
        bf16x8 o;
        o[0] = (__bf16)s0[0]; o[1] = (__bf16)s0[1]; o[2] = (__bf16)s0[2]; o[3] = (__bf16)s0[3];
        o[4] = (__bf16)s1[0]; o[5] = (__bf16)s1[1]; o[6] = (__bf16)s1[2]; o[7] = (__bf16)s1[3];
        *(bf16x8*)(Zb + b0) = o;
    }
}

// ---------------- Pass 2 (MFMA): out[q][e] = (phiQ[q][:] @ KV) / (phiQ[q][:] . Z + EPS)
// NT loads on Q (stream-once per replay; don't depend on L3 residency — R19 showed Q
// stuck half-resident at 2.8 TB/s effective) and NT stores on out (write-once).
__global__ __launch_bounds__(256, 3) void attn_out_mfma(const float* __restrict__ Q,
                                                        const __bf16* __restrict__ KVT,
                                                        const __bf16* __restrict__ Zb,
                                                        float* __restrict__ out) {
    __shared__ __bf16 sKVT[D][D];   // 32 KB, row-XOR-swizzled
    __shared__ __bf16 sQ[QT][D];    // 16 KB, row-XOR-swizzled
    __shared__ __bf16 sZ[D];        // 256 B, linear

    const int bh  = blockIdx.x;
    const int q0  = blockIdx.y * QT;
    const int tid = threadIdx.x;
    const int lane = tid & 63;
    const int wave = tid >> 6;
    const size_t base = (size_t)bh * SEQ * D;

    // stage KVT (bf16 global, cacheable/L3-hot; swizzle: 8-elem seg ^ (row&7))
    {
        const __bf16* kvg = KVT + (size_t)bh * D * D;
#pragma unroll
        for (int j = 0; j < 8; ++j) {
            const int f   = tid + 256 * j;
            const int e   = f >> 4;
            const int seg = f & 15;
            const bf16x8 v = *(const bf16x8*)(kvg + (size_t)f * 8);
            *(bf16x8*)(&sKVT[e][(seg ^ (e & 7)) * 8]) = v;
        }
    }
    if (tid < 16) {
        *(bf16x8*)(&sZ[tid * 8]) = *(const bf16x8*)(Zb + bh * D + tid * 8);
    }
    // stage phi(Q) as bf16, swizzled — NT loads (streaming)
    {
#pragma unroll
        for (int j = 0; j < 8; ++j) {
            const int f  = tid + 256 * j;
            const int r  = f >> 5;
            const int c4 = (f & 31) * 4;
            const f32x4 qv = __builtin_nontemporal_load(
                (const f32x4*)(Q + base + (size_t)(q0 + r) * D + c4));
            bf16x4 qb;
            qb[0] = (__bf16)phi1(qv[0]); qb[1] = (__bf16)phi1(qv[1]);
            qb[2] = (__bf16)phi1(qv[2]); qb[3] = (__bf16)phi1(qv[3]);
            *(bf16x4*)(&sQ[r][c4 ^ ((r & 7) * 8)]) = qb;
        }
    }
    __syncthreads();

    f32x4 acc[8];
#pragma unroll
    for (int et = 0; et < 8; ++et) acc[et] = (f32x4){0.f, 0.f, 0.f, 0.f};
    f32x4 accz = (f32x4){0.f, 0.f, 0.f, 0.f};

    const int qw   = wave * 16;
    const int lrow = lane & 15;
    const int lq   = lane >> 4;

#pragma unroll
    for (int dblk = 0; dblk < 4; ++dblk) {
        const int dbase = dblk * 32 + lq * 8;
        const int arow  = qw + lrow;
        const bf16x8 af = *(const bf16x8*)(&sQ[arow][dbase ^ ((arow & 7) * 8)]);
        const bf16x8 zf = *(const bf16x8*)(&sZ[dbase]);
        accz = __builtin_amdgcn_mfma_f32_16x16x32_bf16(af, zf, accz, 0, 0, 0);
#pragma unroll
        for (int et = 0; et < 8; ++et) {
            const int brow = et * 16 + lrow;
            const bf16x8 bfr = *(const bf16x8*)(&sKVT[brow][dbase ^ ((brow & 7) * 8)]);
            acc[et] = __builtin_amdgcn_mfma_f32_16x16x32_bf16(af, bfr, acc[et], 0, 0, 0);
        }
    }

    // epilogue: C/D layout col=lane&15, row=(lane>>4)*4+reg; NT stores (no L3 alloc)
    float inv[4];
#pragma unroll
    for (int r = 0; r < 4; ++r) inv[r] = 1.0f / (accz[r] + EPS);
    float* ob = out + base + (size_t)(q0 + qw + lq * 4) * D + lrow;
#pragma unroll
    for (int r = 0; r < 4; ++r) {
#pragma unroll
        for (int et = 0; et < 8; ++et) {
            __builtin_nontemporal_store(acc[et][r] * inv[r], &ob[(size_t)r * D + et * 16]);
        }
    }
}

extern "C" void kernel_launch(void* const* d_in, const int* in_sizes, int n_in,
                              void* d_out, int out_size, void* d_ws, size_t ws_size,
                              hipStream_t stream) {
    const float* Q = (const float*)d_in[0];
    const float* K = (const float*)d_in[1];
    const float* V = (const float*)d_in[2];
    float* out = (float*)d_out;

    // ws layout: [KVTp: P*NBH*D*D f32][Zp: P*NBH*D f32][KVT: NBH*D*D bf16][Zb: NBH*D bf16]
    const size_t per_split_f = (size_t)NBH * D * D + (size_t)NBH * D;
    const size_t bf16_bytes  = ((size_t)NBH * D * D + (size_t)NBH * D) * sizeof(__bf16);
    int P = 8;
    while (P > 1 && (size_t)P * per_split_f * sizeof(float) + bf16_bytes > ws_size) P >>= 1;
    const int chunk = SEQ / P;   // 512 at P=8; chunk/TK = 32 tiles (> prologue depth 3)

    float*  KVTp = (float*)d_ws;
    float*  Zp   = KVTp + (size_t)P * NBH * D * D;
    __bf16* KVT  = (__bf16*)(Zp + (size_t)P * NBH * D);
    __bf16* Zb   = KVT + (size_t)NBH * D * D;

    kv_partial_mfma<<<dim3(P, NBH), 512, 0, stream>>>(K, V, KVTp, Zp, chunk);

    constexpr int RED_ITEMS = NBH * D * D / 8 + NBH * D / 8;
    reduce_bf16_kernel<<<(RED_ITEMS + 255) / 256, 256, 0, stream>>>(KVTp, Zp, KVT, Zb, P);

    attn_out_mfma<<<dim3(NBH, SEQ / QT), 256, 0, stream>>>(Q, KVT, Zb, out);
}

// Round 21
// 107.327 us; speedup vs baseline: 1.0574x; 1.0574x over previous
//
#include <hip/hip_runtime.h>
#include <stdint.h>

#define EPS 1e-6f

constexpr int D    = 128;   // head_dim
constexpr int SEQ  = 4096;  // seq_len
constexpr int NBH  = 64;    // bsz*num_heads
constexpr int TK   = 16;    // k rows per LDS tile (pass 1)
constexpr int QT   = 64;    // q rows per block (pass 2)

typedef __attribute__((ext_vector_type(8)))  __bf16 bf16x8;
typedef __attribute__((ext_vector_type(4)))  __bf16 bf16x4;
typedef __attribute__((ext_vector_type(4)))  float  f32x4;
typedef __attribute__((ext_vector_type(16))) float  f32x16;

typedef const __attribute__((address_space(1))) uint32_t* as1_u32p;
typedef __attribute__((address_space(3))) uint32_t*       as3_u32p;

__device__ __forceinline__ float phi1(float x) {
    // elu(x)+1 : x>0 -> x+1 ; x<=0 -> exp(x). Branchless.
    return fmaxf(x, 0.0f) + __expf(fminf(x, 0.0f));
}

// ---------------- Pass 1 (MFMA + global_load_lds, depth-3 pipeline, NT loads):
// KVTp[split][bh][e][d] = sum_k V[k][e]*phiK[k][d]  (f32 partials)
// aux=2 (CPol NT) on the K/V streams (268 MB > L3; cacheable reads thrashed Infinity
// Cache and pinned service at ~2.6 TB/s across 11 structural variants R5-R17).
// NT bypass unlocked pass 1: 103 -> ~30 µs (R18). Partial stores stay CACHEABLE
// (R19 config — R20's NT-everywhere was a small regression).
__global__ __launch_bounds__(512, 4) void kv_partial_mfma(const float* __restrict__ K,
                                                          const float* __restrict__ V,
                                                          float* __restrict__ KVTp,
                                                          float* __restrict__ Zp,
                                                          int chunk) {
    __shared__ float stile[4][2][TK][D];   // [buf][K|V][k][col] = 64 KB -> 2 blocks/CU

    const int split = blockIdx.x, bh = blockIdx.y;
    const int tid  = threadIdx.x;
    const int lane = tid & 63;
    const int wave = tid >> 6;
    const int k0   = split * chunk;
    const size_t base = (size_t)bh * SEQ * D;

    // staging role: waves 0-3 issue K tile, waves 4-7 issue V tile; 2 x 16B per thread
    const int  mat = wave >> 2;             // 0 = K, 1 = V
    const int  w4  = wave & 3;
    const float* __restrict__ src = mat ? V : K;
    const int eoff0 = (w4 * 2 + 0) * 256 + lane * 4;  // float offset within [16][128] tile
    const int eoff1 = (w4 * 2 + 1) * 256 + lane * 4;

    // compute role: 2e x 4d wave grid
    const int we = wave >> 2;                        // 0..1 -> e-base we*64
    const int wd = wave & 3;                         // 0..3 -> d-strip wd*32
    const int er0 = we * 64 + (lane & 31);           // A row (e), strip 0
    const int er1 = er0 + 32;                        // A row (e), strip 1
    const int dr  = wd * 32 + (lane & 31);           // B col (d)
    const int kh  = (lane >> 5) * 8;                 // k-half of the 16-k step

    f32x16 acc0, acc1;
#pragma unroll
    for (int i = 0; i < 16; ++i) { acc0[i] = 0.f; acc1[i] = 0.f; }
    float zacc = 0.f;
    const bool doZ = (we == 0);   // waves 0-3 own Z for their own d-strip

    const int tiles = chunk / TK;

#define ISSUE(BUF, T) { \
        const float* g = src + base + (size_t)(k0 + (T) * TK) * D; \
        float* l = &stile[BUF][mat][0][0]; \
        __builtin_amdgcn_global_load_lds((as1_u32p)(const void*)(g + eoff0), \
                                         (as3_u32p)(void*)(l + eoff0), 16, 0, 2); \
        __builtin_amdgcn_global_load_lds((as1_u32p)(const void*)(g + eoff1), \
                                         (as3_u32p)(void*)(l + eoff1), 16, 0, 2); }

    // prologue: 3 tiles in flight (6 loads/wave)
    ISSUE(0, 0)
    ISSUE(1, 1)
    ISSUE(2, 2)

    for (int t = 0; t < tiles; ++t) {
        const int buf = t & 3;
        if (t + 3 < tiles) {
            ISSUE((t + 3) & 3, t + 3)
            asm volatile("s_waitcnt vmcnt(6)" ::: "memory");  // t's 2 done; 6 in flight
        } else if (t + 2 < tiles) {
            asm volatile("s_waitcnt vmcnt(4)" ::: "memory");
        } else if (t + 1 < tiles) {
            asm volatile("s_waitcnt vmcnt(2)" ::: "memory");
        } else {
            asm volatile("s_waitcnt vmcnt(0)" ::: "memory");
        }
        __builtin_amdgcn_s_barrier();        // all waves' tile-t writes visible
        __builtin_amdgcn_sched_barrier(0);

        const float* kt = &stile[buf][0][0][0];
        const float* vt = &stile[buf][1][0][0];

        bf16x8 av0, av1, bk;
#pragma unroll
        for (int i = 0; i < 8; ++i) {
            const float fv0 = vt[(kh + i) * D + er0];
            const float fv1 = vt[(kh + i) * D + er1];
            const float p   = phi1(kt[(kh + i) * D + dr]);
            av0[i] = (__bf16)fv0;
            av1[i] = (__bf16)fv1;
            bk[i]  = (__bf16)p;
            if (doZ) zacc += p;
        }
        acc0 = __builtin_amdgcn_mfma_f32_32x32x16_bf16(av0, bk, acc0, 0, 0, 0);
        acc1 = __builtin_amdgcn_mfma_f32_32x32x16_bf16(av1, bk, acc1, 0, 0, 0);

        asm volatile("s_waitcnt lgkmcnt(0)" ::: "memory");   // my ds_reads retired
        __builtin_amdgcn_s_barrier();                         // buf reusable at t+1's ISSUE
        __builtin_amdgcn_sched_barrier(0);
    }
#undef ISSUE

    // store C partials (f32). C/D: col = lane&31, row = (reg&3) + 8*(reg>>2) + 4*(lane>>5)
    float* kvb = KVTp + ((size_t)split * NBH + bh) * D * D;
    const int ebase = we * 64 + 4 * (lane >> 5);
    const int dcol  = wd * 32 + (lane & 31);
#pragma unroll
    for (int r = 0; r < 16; ++r) {
        const int e = ebase + (r & 3) + 8 * (r >> 2);
        kvb[(size_t)e * D + dcol]        = acc0[r];
        kvb[(size_t)(e + 32) * D + dcol] = acc1[r];
    }

    // Z: lane l covers k-half kh at d = dr; lane l^32 covers the other k-half
    if (doZ) {
        zacc += __shfl_xor(zacc, 32);
        if (lane < 32) {
            Zp[((size_t)split * NBH + bh) * D + wd * 32 + lane] = zacc;
        }
    }
}

// ---------------- Reduce partials -> bf16: KVT[bh][e][d], Zb[bh][d]
__global__ __launch_bounds__(256) void reduce_bf16_kernel(const float* __restrict__ KVTp,
                                                          const float* __restrict__ Zp,
                                                          __bf16* __restrict__ KVT,
                                                          __bf16* __restrict__ Zb,
                                                          int P) {
    constexpr int KVF8 = NBH * D * D / 8;  // 131072
    constexpr int ZF8  = NBH * D / 8;      // 1024
    const int idx = blockIdx.x * 256 + threadIdx.x;
    if (idx < KVF8) {
        const size_t b0 = (size_t)idx * 8;
        float4 s0 = *(const float4*)(KVTp + b0);
        float4 s1 = *(const float4*)(KVTp + b0 + 4);
        for (int s = 1; s < P; ++s) {
            const float* p = KVTp + (size_t)s * NBH * D * D + b0;
            const float4 a = *(const float4*)(p);
            const float4 b = *(const float4*)(p + 4);
            s0.x += a.x; s0.y += a.y; s0.z += a.z; s0.w += a.w;
            s1.x += b.x; s1.y += b.y; s1.z += b.z; s1.w += b.w;
        }
        bf16x8 o;
        o[0] = (__bf16)s0.x; o[1] = (__bf16)s0.y; o[2] = (__bf16)s0.z; o[3] = (__bf16)s0.w;
        o[4] = (__bf16)s1.x; o[5] = (__bf16)s1.y; o[6] = (__bf16)s1.z; o[7] = (__bf16)s1.w;
        *(bf16x8*)(KVT + b0) = o;
    } else if (idx < KVF8 + ZF8) {
        const size_t b0 = (size_t)(idx - KVF8) * 8;
        float4 s0 = *(const float4*)(Zp + b0);
        float4 s1 = *(const float4*)(Zp + b0 + 4);
        for (int s = 1; s < P; ++s) {
            const float* p = Zp + (size_t)s * NBH * D + b0;
            const float4 a = *(const float4*)(p);
            const float4 b = *(const float4*)(p + 4);
            s0.x += a.x; s0.y += a.y; s0.z += a.z; s0.w += a.w;
            s1.x += b.x; s1.y += b.y; s1.z += b.z; s1.w += b.w;
        }
        bf16x8 o;
        o[0] = (__bf16)s0.x; o[1] = (__bf16)s0.y; o[2] = (__bf16)s0.z; o[3] = (__bf16)s0.w;
        o[4] = (__bf16)s1.x; o[5] = (__bf16)s1.y; o[6] = (__bf16)s1.z; o[7] = (__bf16)s1.w;
        *(bf16x8*)(Zb + b0) = o;
    }
}

// ---------------- Pass 2 (MFMA): out[q][e] = (phiQ[q][:] @ KV) / (phiQ[q][:] . Z + EPS)
// Q loads cacheable (L3 hits are real — R20's NT-load was a regression). Output goes
// through an LDS transpose (sKVT reused after MFMA) so NT stores are fully-coalesced
// 16B/lane full-row bursts (R19 epilogue's scattered 4B stores inflated WRITE_SIZE
// 131 -> 159 MB).
__global__ __launch_bounds__(256, 3) void attn_out_mfma(const float* __restrict__ Q,
                                                        const __bf16* __restrict__ KVT,
                                                        const __bf16* __restrict__ Zb,
                                                        float* __restrict__ out) {
    __shared__ __bf16 sKVT[D][D];   // 32 KB, row-XOR-swizzled; reused as f32 out-tile
    __shared__ __bf16 sQ[QT][D];    // 16 KB, row-XOR-swizzled
    __shared__ __bf16 sZ[D];        // 256 B, linear

    const int bh  = blockIdx.x;
    const int q0  = blockIdx.y * QT;
    const int tid = threadIdx.x;
    const int lane = tid & 63;
    const int wave = tid >> 6;
    const size_t base = (size_t)bh * SEQ * D;

    // stage KVT (bf16 global, cacheable/L3-hot; swizzle: 8-elem seg ^ (row&7))
    {
        const __bf16* kvg = KVT + (size_t)bh * D * D;
#pragma unroll
        for (int j = 0; j < 8; ++j) {
            const int f   = tid + 256 * j;
            const int e   = f >> 4;
            const int seg = f & 15;
            const bf16x8 v = *(const bf16x8*)(kvg + (size_t)f * 8);
            *(bf16x8*)(&sKVT[e][(seg ^ (e & 7)) * 8]) = v;
        }
    }
    if (tid < 16) {
        *(bf16x8*)(&sZ[tid * 8]) = *(const bf16x8*)(Zb + bh * D + tid * 8);
    }
    // stage phi(Q) as bf16, swizzled (cacheable loads)
    {
#pragma unroll
        for (int j = 0; j < 8; ++j) {
            const int f  = tid + 256 * j;
            const int r  = f >> 5;
            const int c4 = (f & 31) * 4;
            const float4 qv = *(const float4*)(Q + base + (size_t)(q0 + r) * D + c4);
            bf16x4 qb;
            qb[0] = (__bf16)phi1(qv.x); qb[1] = (__bf16)phi1(qv.y);
            qb[2] = (__bf16)phi1(qv.z); qb[3] = (__bf16)phi1(qv.w);
            *(bf16x4*)(&sQ[r][c4 ^ ((r & 7) * 8)]) = qb;
        }
    }
    __syncthreads();

    f32x4 acc[8];
#pragma unroll
    for (int et = 0; et < 8; ++et) acc[et] = (f32x4){0.f, 0.f, 0.f, 0.f};
    f32x4 accz = (f32x4){0.f, 0.f, 0.f, 0.f};

    const int qw   = wave * 16;
    const int lrow = lane & 15;
    const int lq   = lane >> 4;

#pragma unroll
    for (int dblk = 0; dblk < 4; ++dblk) {
        const int dbase = dblk * 32 + lq * 8;
        const int arow  = qw + lrow;
        const bf16x8 af = *(const bf16x8*)(&sQ[arow][dbase ^ ((arow & 7) * 8)]);
        const bf16x8 zf = *(const bf16x8*)(&sZ[dbase]);
        accz = __builtin_amdgcn_mfma_f32_16x16x32_bf16(af, zf, accz, 0, 0, 0);
#pragma unroll
        for (int et = 0; et < 8; ++et) {
            const int brow = et * 16 + lrow;
            const bf16x8 bfr = *(const bf16x8*)(&sKVT[brow][dbase ^ ((brow & 7) * 8)]);
            acc[et] = __builtin_amdgcn_mfma_f32_16x16x32_bf16(af, bfr, acc[et], 0, 0, 0);
        }
    }

    // epilogue: C/D layout col=lane&15, row=(lane>>4)*4+reg.
    // Deposit into LDS (reusing sKVT as a 64x128 f32 tile), then stream out as
    // fully-coalesced 16B NT stores (one instruction = one 512B row per 32 lanes).
    __syncthreads();   // all MFMA reads of sKVT/sQ complete before reuse
    float* sOut = (float*)&sKVT[0][0];   // 32 KB == QT*D*4
    float inv[4];
#pragma unroll
    for (int r = 0; r < 4; ++r) inv[r] = 1.0f / (accz[r] + EPS);
#pragma unroll
    for (int r = 0; r < 4; ++r) {
        const int row = qw + lq * 4 + r;
#pragma unroll
        for (int et = 0; et < 8; ++et) {
            sOut[row * D + lrow + et * 16] = acc[et][r] * inv[r];
        }
    }
    __syncthreads();
    {
        float* ob = out + base + (size_t)q0 * D;
#pragma unroll
        for (int j = 0; j < 8; ++j) {
            const int f  = tid + 256 * j;      // 2048 float4 chunks = 64 rows x 32
            const int r  = f >> 5;
            const int c4 = (f & 31) * 4;
            const f32x4 v = *(const f32x4*)(sOut + r * D + c4);
            __builtin_nontemporal_store(v, (f32x4*)(ob + (size_t)r * D + c4));
        }
    }
}

extern "C" void kernel_launch(void* const* d_in, const int* in_sizes, int n_in,
                              void* d_out, int out_size, void* d_ws, size_t ws_size,
                              hipStream_t stream) {
    const float* Q = (const float*)d_in[0];
    const float* K = (const float*)d_in[1];
    const float* V = (const float*)d_in[2];
    float* out = (float*)d_out;

    // ws layout: [KVTp: P*NBH*D*D f32][Zp: P*NBH*D f32][KVT: NBH*D*D bf16][Zb: NBH*D bf16]
    const size_t per_split_f = (size_t)NBH * D * D + (size_t)NBH * D;
    const size_t bf16_bytes  = ((size_t)NBH * D * D + (size_t)NBH * D) * sizeof(__bf16);
    int P = 8;
    while (P > 1 && (size_t)P * per_split_f * sizeof(float) + bf16_bytes > ws_size) P >>= 1;
    const int chunk = SEQ / P;   // 512 at P=8; chunk/TK = 32 tiles (> prologue depth 3)

    float*  KVTp = (float*)d_ws;
    float*  Zp   = KVTp + (size_t)P * NBH * D * D;
    __bf16* KVT  = (__bf16*)(Zp + (size_t)P * NBH * D);
    __bf16* Zb   = KVT + (size_t)NBH * D * D;

    kv_partial_mfma<<<dim3(P, NBH), 512, 0, stream>>>(K, V, KVTp, Zp, chunk);

    constexpr int RED_ITEMS = NBH * D * D / 8 + NBH * D / 8;
    reduce_bf16_kernel<<<(RED_ITEMS + 255) / 256, 256, 0, stream>>>(KVTp, Zp, KVT, Zb, P);

    attn_out_mfma<<<dim3(NBH, SEQ / QT), 256, 0, stream>>>(Q, KVT, Zb, out);
}

// Round 22
// 101.738 us; speedup vs baseline: 1.1155x; 1.0549x over previous
//
#include <hip/hip_runtime.h>
#include <stdint.h>

#define EPS 1e-6f

constexpr int D    = 128;   // head_dim
constexpr int SEQ  = 4096;  // seq_len
constexpr int NBH  = 64;    // bsz*num_heads
constexpr int TK   = 16;    // k rows per LDS tile (pass 1)
constexpr int QT   = 64;    // q rows per block (pass 2)

typedef __attribute__((ext_vector_type(8)))  __bf16 bf16x8;
typedef __attribute__((ext_vector_type(4)))  __bf16 bf16x4;
typedef __attribute__((ext_vector_type(4)))  float  f32x4;
typedef __attribute__((ext_vector_type(16))) float  f32x16;

typedef const __attribute__((address_space(1))) uint32_t* as1_u32p;
typedef __attribute__((address_space(3))) uint32_t*       as3_u32p;

__device__ __forceinline__ float phi1(float x) {
    // elu(x)+1 : x>0 -> x+1 ; x<=0 -> exp(x). Branchless.
    return fmaxf(x, 0.0f) + __expf(fminf(x, 0.0f));
}

// ---------------- Pass 1 (MFMA + global_load_lds, depth-3 pipeline, NT loads):
// KVTp[split][bh][e][d] = sum_k V[k][e]*phiK[k][d]  (f32 partials)
// aux=2 (CPol NT) on the K/V streams (268 MB > L3; cacheable reads thrashed Infinity
// Cache and pinned service ~2.6 TB/s across 11 structural variants R5-R17). NT bypass
// unlocked pass 1: 103 -> ~30 µs (R18). Partial stores cacheable (R19 config).
__global__ __launch_bounds__(512, 4) void kv_partial_mfma(const float* __restrict__ K,
                                                          const float* __restrict__ V,
                                                          float* __restrict__ KVTp,
                                                          float* __restrict__ Zp,
                                                          int chunk) {
    __shared__ float stile[4][2][TK][D];   // [buf][K|V][k][col] = 64 KB -> 2 blocks/CU

    const int split = blockIdx.x, bh = blockIdx.y;
    const int tid  = threadIdx.x;
    const int lane = tid & 63;
    const int wave = tid >> 6;
    const int k0   = split * chunk;
    const size_t base = (size_t)bh * SEQ * D;

    // staging role: waves 0-3 issue K tile, waves 4-7 issue V tile; 2 x 16B per thread
    const int  mat = wave >> 2;             // 0 = K, 1 = V
    const int  w4  = wave & 3;
    const float* __restrict__ src = mat ? V : K;
    const int eoff0 = (w4 * 2 + 0) * 256 + lane * 4;  // float offset within [16][128] tile
    const int eoff1 = (w4 * 2 + 1) * 256 + lane * 4;

    // compute role: 2e x 4d wave grid
    const int we = wave >> 2;                        // 0..1 -> e-base we*64
    const int wd = wave & 3;                         // 0..3 -> d-strip wd*32
    const int er0 = we * 64 + (lane & 31);           // A row (e), strip 0
    const int er1 = er0 + 32;                        // A row (e), strip 1
    const int dr  = wd * 32 + (lane & 31);           // B col (d)
    const int kh  = (lane >> 5) * 8;                 // k-half of the 16-k step

    f32x16 acc0, acc1;
#pragma unroll
    for (int i = 0; i < 16; ++i) { acc0[i] = 0.f; acc1[i] = 0.f; }
    float zacc = 0.f;
    const bool doZ = (we == 0);   // waves 0-3 own Z for their own d-strip

    const int tiles = chunk / TK;

#define ISSUE(BUF, T) { \
        const float* g = src + base + (size_t)(k0 + (T) * TK) * D; \
        float* l = &stile[BUF][mat][0][0]; \
        __builtin_amdgcn_global_load_lds((as1_u32p)(const void*)(g + eoff0), \
                                         (as3_u32p)(void*)(l + eoff0), 16, 0, 2); \
        __builtin_amdgcn_global_load_lds((as1_u32p)(const void*)(g + eoff1), \
                                         (as3_u32p)(void*)(l + eoff1), 16, 0, 2); }

    // prologue: 3 tiles in flight (6 loads/wave)
    ISSUE(0, 0)
    ISSUE(1, 1)
    ISSUE(2, 2)

    for (int t = 0; t < tiles; ++t) {
        const int buf = t & 3;
        if (t + 3 < tiles) {
            ISSUE((t + 3) & 3, t + 3)
            asm volatile("s_waitcnt vmcnt(6)" ::: "memory");  // t's 2 done; 6 in flight
        } else if (t + 2 < tiles) {
            asm volatile("s_waitcnt vmcnt(4)" ::: "memory");
        } else if (t + 1 < tiles) {
            asm volatile("s_waitcnt vmcnt(2)" ::: "memory");
        } else {
            asm volatile("s_waitcnt vmcnt(0)" ::: "memory");
        }
        __builtin_amdgcn_s_barrier();        // all waves' tile-t writes visible
        __builtin_amdgcn_sched_barrier(0);

        const float* kt = &stile[buf][0][0][0];
        const float* vt = &stile[buf][1][0][0];

        bf16x8 av0, av1, bk;
#pragma unroll
        for (int i = 0; i < 8; ++i) {
            const float fv0 = vt[(kh + i) * D + er0];
            const float fv1 = vt[(kh + i) * D + er1];
            const float p   = phi1(kt[(kh + i) * D + dr]);
            av0[i] = (__bf16)fv0;
            av1[i] = (__bf16)fv1;
            bk[i]  = (__bf16)p;
            if (doZ) zacc += p;
        }
        acc0 = __builtin_amdgcn_mfma_f32_32x32x16_bf16(av0, bk, acc0, 0, 0, 0);
        acc1 = __builtin_amdgcn_mfma_f32_32x32x16_bf16(av1, bk, acc1, 0, 0, 0);

        asm volatile("s_waitcnt lgkmcnt(0)" ::: "memory");   // my ds_reads retired
        __builtin_amdgcn_s_barrier();                         // buf reusable at t+1's ISSUE
        __builtin_amdgcn_sched_barrier(0);
    }
#undef ISSUE

    // store C partials (f32). C/D: col = lane&31, row = (reg&3) + 8*(reg>>2) + 4*(lane>>5)
    float* kvb = KVTp + ((size_t)split * NBH + bh) * D * D;
    const int ebase = we * 64 + 4 * (lane >> 5);
    const int dcol  = wd * 32 + (lane & 31);
#pragma unroll
    for (int r = 0; r < 16; ++r) {
        const int e = ebase + (r & 3) + 8 * (r >> 2);
        kvb[(size_t)e * D + dcol]        = acc0[r];
        kvb[(size_t)(e + 32) * D + dcol] = acc1[r];
    }

    // Z: lane l covers k-half kh at d = dr; lane l^32 covers the other k-half
    if (doZ) {
        zacc += __shfl_xor(zacc, 32);
        if (lane < 32) {
            Zp[((size_t)split * NBH + bh) * D + wd * 32 + lane] = zacc;
        }
    }
}

// ---------------- Reduce partials -> bf16: KVT[bh][e][d], Zb[bh][d]
__global__ __launch_bounds__(256) void reduce_bf16_kernel(const float* __restrict__ KVTp,
                                                          const float* __restrict__ Zp,
                                                          __bf16* __restrict__ KVT,
                                                          __bf16* __restrict__ Zb,
                                                          int P) {
    constexpr int KVF8 = NBH * D * D / 8;  // 131072
    constexpr int ZF8  = NBH * D / 8;      // 1024
    const int idx = blockIdx.x * 256 + threadIdx.x;
    if (idx < KVF8) {
        const size_t b0 = (size_t)idx * 8;
        float4 s0 = *(const float4*)(KVTp + b0);
        float4 s1 = *(const float4*)(KVTp + b0 + 4);
        for (int s = 1; s < P; ++s) {
            const float* p = KVTp + (size_t)s * NBH * D * D + b0;
            const float4 a = *(const float4*)(p);
            const float4 b = *(const float4*)(p + 4);
            s0.x += a.x; s0.y += a.y; s0.z += a.z; s0.w += a.w;
            s1.x += b.x; s1.y += b.y; s1.z += b.z; s1.w += b.w;
        }
        bf16x8 o;
        o[0] = (__bf16)s0.x; o[1] = (__bf16)s0.y; o[2] = (__bf16)s0.z; o[3] = (__bf16)s0.w;
        o[4] = (__bf16)s1.x; o[5] = (__bf16)s1.y; o[6] = (__bf16)s1.z; o[7] = (__bf16)s1.w;
        *(bf16x8*)(KVT + b0) = o;
    } else if (idx < KVF8 + ZF8) {
        const size_t b0 = (size_t)(idx - KVF8) * 8;
        float4 s0 = *(const float4*)(Zp + b0);
        float4 s1 = *(const float4*)(Zp + b0 + 4);
        for (int s = 1; s < P; ++s) {
            const float* p = Zp + (size_t)s * NBH * D + b0;
            const float4 a = *(const float4*)(p);
            const float4 b = *(const float4*)(p + 4);
            s0.x += a.x; s0.y += a.y; s0.z += a.z; s0.w += a.w;
            s1.x += b.x; s1.y += b.y; s1.z += b.z; s1.w += b.w;
        }
        bf16x8 o;
        o[0] = (__bf16)s0.x; o[1] = (__bf16)s0.y; o[2] = (__bf16)s0.z; o[3] = (__bf16)s0.w;
        o[4] = (__bf16)s1.x; o[5] = (__bf16)s1.y; o[6] = (__bf16)s1.z; o[7] = (__bf16)s1.w;
        *(bf16x8*)(Zb + b0) = o;
    }
}

// ---------------- Pass 2 (MFMA): out[q][e] = (phiQ[q][:] @ KV) / (phiQ[q][:] . Z + EPS)
// R22: Q A-fragments loaded DIRECTLY global->register (lanes {l,l+16,l+32,l+48} read
// 4 consecutive 32B segments of one row = 128B contiguous; Q still read exactly once).
// Drops the 16 KB sQ stage -> 33 KB LDS -> 4 blocks/CU, and shortens the per-block
// critical path to {stage KVT -> MFMA -> LDS-coalesced NT store}.
__global__ __launch_bounds__(256, 4) void attn_out_mfma(const float* __restrict__ Q,
                                                        const __bf16* __restrict__ KVT,
                                                        const __bf16* __restrict__ Zb,
                                                        float* __restrict__ out) {
    __shared__ __bf16 sKVT[D][D];   // 32 KB, row-XOR-swizzled; reused as f32 out-tile
    __shared__ __bf16 sZ[D];        // 256 B, linear

    const int bh  = blockIdx.x;
    const int q0  = blockIdx.y * QT;
    const int tid = threadIdx.x;
    const int lane = tid & 63;
    const int wave = tid >> 6;
    const size_t base = (size_t)bh * SEQ * D;

    const int qw   = wave * 16;
    const int lrow = lane & 15;
    const int lq   = lane >> 4;

    // issue Q fragment loads early (f32, cacheable — ~50% L3-hit per R19/R21 counters)
    const float* qrow = Q + base + (size_t)(q0 + qw + lrow) * D + lq * 8;
    f32x4 qv0_0 = *(const f32x4*)(qrow + 0 * 32);
    f32x4 qv1_0 = *(const f32x4*)(qrow + 0 * 32 + 4);
    f32x4 qv0_1 = *(const f32x4*)(qrow + 1 * 32);
    f32x4 qv1_1 = *(const f32x4*)(qrow + 1 * 32 + 4);
    f32x4 qv0_2 = *(const f32x4*)(qrow + 2 * 32);
    f32x4 qv1_2 = *(const f32x4*)(qrow + 2 * 32 + 4);
    f32x4 qv0_3 = *(const f32x4*)(qrow + 3 * 32);
    f32x4 qv1_3 = *(const f32x4*)(qrow + 3 * 32 + 4);

    // stage KVT (bf16 global, cacheable/L3-hot; swizzle: 8-elem seg ^ (row&7))
    {
        const __bf16* kvg = KVT + (size_t)bh * D * D;
#pragma unroll
        for (int j = 0; j < 8; ++j) {
            const int f   = tid + 256 * j;
            const int e   = f >> 4;
            const int seg = f & 15;
            const bf16x8 v = *(const bf16x8*)(kvg + (size_t)f * 8);
            *(bf16x8*)(&sKVT[e][(seg ^ (e & 7)) * 8]) = v;
        }
    }
    if (tid < 16) {
        *(bf16x8*)(&sZ[tid * 8]) = *(const bf16x8*)(Zb + bh * D + tid * 8);
    }
    __syncthreads();

    f32x4 acc[8];
#pragma unroll
    for (int et = 0; et < 8; ++et) acc[et] = (f32x4){0.f, 0.f, 0.f, 0.f};
    f32x4 accz = (f32x4){0.f, 0.f, 0.f, 0.f};

#define P2_DBLK(DBLK, QV0, QV1) { \
        const int dbase = DBLK * 32 + lq * 8; \
        bf16x8 af; \
        af[0] = (__bf16)phi1(QV0[0]); af[1] = (__bf16)phi1(QV0[1]); \
        af[2] = (__bf16)phi1(QV0[2]); af[3] = (__bf16)phi1(QV0[3]); \
        af[4] = (__bf16)phi1(QV1[0]); af[5] = (__bf16)phi1(QV1[1]); \
        af[6] = (__bf16)phi1(QV1[2]); af[7] = (__bf16)phi1(QV1[3]); \
        const bf16x8 zf = *(const bf16x8*)(&sZ[dbase]); \
        accz = __builtin_amdgcn_mfma_f32_16x16x32_bf16(af, zf, accz, 0, 0, 0); \
        _Pragma("unroll") \
        for (int et = 0; et < 8; ++et) { \
            const int brow = et * 16 + lrow; \
            const bf16x8 bfr = *(const bf16x8*)(&sKVT[brow][dbase ^ ((brow & 7) * 8)]); \
            acc[et] = __builtin_amdgcn_mfma_f32_16x16x32_bf16(af, bfr, acc[et], 0, 0, 0); \
        } }

    P2_DBLK(0, qv0_0, qv1_0)
    P2_DBLK(1, qv0_1, qv1_1)
    P2_DBLK(2, qv0_2, qv1_2)
    P2_DBLK(3, qv0_3, qv1_3)
#undef P2_DBLK

    // epilogue: C/D layout col=lane&15, row=(lane>>4)*4+reg.
    // Deposit into LDS (reusing sKVT as a 64x128 f32 tile), then stream out as
    // fully-coalesced 16B NT stores (one instruction = one 512B row per 32 lanes).
    __syncthreads();   // all MFMA reads of sKVT complete before reuse
    float* sOut = (float*)&sKVT[0][0];   // 32 KB == QT*D*4
    float inv[4];
#pragma unroll
    for (int r = 0; r < 4; ++r) inv[r] = 1.0f / (accz[r] + EPS);
#pragma unroll
    for (int r = 0; r < 4; ++r) {
        const int row = qw + lq * 4 + r;
#pragma unroll
        for (int et = 0; et < 8; ++et) {
            sOut[row * D + lrow + et * 16] = acc[et][r] * inv[r];
        }
    }
    __syncthreads();
    {
        float* ob = out + base + (size_t)q0 * D;
#pragma unroll
        for (int j = 0; j < 8; ++j) {
            const int f  = tid + 256 * j;      // 2048 float4 chunks = 64 rows x 32
            const int r  = f >> 5;
            const int c4 = (f & 31) * 4;
            const f32x4 v = *(const f32x4*)(sOut + r * D + c4);
            __builtin_nontemporal_store(v, (f32x4*)(ob + (size_t)r * D + c4));
        }
    }
}

extern "C" void kernel_launch(void* const* d_in, const int* in_sizes, int n_in,
                              void* d_out, int out_size, void* d_ws, size_t ws_size,
                              hipStream_t stream) {
    const float* Q = (const float*)d_in[0];
    const float* K = (const float*)d_in[1];
    const float* V = (const float*)d_in[2];
    float* out = (float*)d_out;

    // ws layout: [KVTp: P*NBH*D*D f32][Zp: P*NBH*D f32][KVT: NBH*D*D bf16][Zb: NBH*D bf16]
    const size_t per_split_f = (size_t)NBH * D * D + (size_t)NBH * D;
    const size_t bf16_bytes  = ((size_t)NBH * D * D + (size_t)NBH * D) * sizeof(__bf16);
    int P = 8;
    while (P > 1 && (size_t)P * per_split_f * sizeof(float) + bf16_bytes > ws_size) P >>= 1;
    const int chunk = SEQ / P;   // 512 at P=8; chunk/TK = 32 tiles (> prologue depth 3)

    float*  KVTp = (float*)d_ws;
    float*  Zp   = KVTp + (size_t)P * NBH * D * D;
    __bf16* KVT  = (__bf16*)(Zp + (size_t)P * NBH * D);
    __bf16* Zb   = KVT + (size_t)NBH * D * D;

    kv_partial_mfma<<<dim3(P, NBH), 512, 0, stream>>>(K, V, KVTp, Zp, chunk);

    constexpr int RED_ITEMS = NBH * D * D / 8 + NBH * D / 8;
    reduce_bf16_kernel<<<(RED_ITEMS + 255) / 256, 256, 0, stream>>>(KVTp, Zp, KVT, Zb, P);

    attn_out_mfma<<<dim3(NBH, SEQ / QT), 256, 0, stream>>>(Q, KVT, Zb, out);
}